// Round 3
// baseline (2236.889 us; speedup 1.0000x reference)
//
#include <hip/hip_runtime.h>

#define NB 64
#define HW 4096           // 64*64

// ---------------------------------------------------------------------------
// K0: transpose W2 [48,128] -> W2T [128,48] (contiguous rows for s_load).
// ---------------------------------------------------------------------------
__global__ __launch_bounds__(256) void k_prep(
    const float* __restrict__ W2, float* __restrict__ W2T) {
  for (int i = threadIdx.x; i < 6144; i += 256) {
    int o = i / 48;
    int c = i - o * 48;
    W2T[i] = W2[c * 128 + o];
  }
}

// ---------------------------------------------------------------------------
// K1: perceive (fixed stencil) + pre_life + zero the atomic accumulators.
// ---------------------------------------------------------------------------
__global__ __launch_bounds__(256) void k_perceive(
    const float* __restrict__ x, float* __restrict__ y_chw,
    float* __restrict__ y0_hwc, float* __restrict__ prelife,
    float* __restrict__ att_zero) {
  int t = threadIdx.x;
  if (blockIdx.x == 0) {
    for (int i = t; i < 649; i += 256) att_zero[i] = 0.f;
  }
  int pix = blockIdx.x * 256 + t;
  int b = pix >> 12;
  int hw = pix & 4095;
  int h = hw >> 6, w = hw & 63;
  const float* xp = x + (size_t)pix * 8;
  bool hm = h > 0, hp = h < 63, wm = w > 0, wp = w < 63;

  float mx = -1e30f;
  #pragma unroll
  for (int di = -1; di <= 1; ++di) {
    if ((unsigned)(h + di) > 63u) continue;
    #pragma unroll
    for (int dj = -1; dj <= 1; ++dj) {
      if ((unsigned)(w + dj) > 63u) continue;
      mx = fmaxf(mx, xp[(di * 64 + dj) * 8 + 3]);
    }
  }
  prelife[pix] = (mx > 0.1f) ? 1.f : 0.f;

  float* yb = y_chw + (size_t)b * 24 * HW + hw;
  bool b0 = (b == 0);
  #pragma unroll
  for (int c = 0; c < 8; ++c) {
    float ctr = xp[c];
    float a00 = (hm && wm) ? xp[(-65) * 8 + c] : 0.f;
    float a02 = (hm && wp) ? xp[(-63) * 8 + c] : 0.f;
    float a20 = (hp && wm) ? xp[(63) * 8 + c] : 0.f;
    float a22 = (hp && wp) ? xp[(65) * 8 + c] : 0.f;
    float d = (a00 + a02 + a20 + a22) * 0.125f;   // dxk == dyk (symmetric)
    yb[(size_t)(c * 3 + 0) * HW] = ctr;
    yb[(size_t)(c * 3 + 1) * HW] = d;
    yb[(size_t)(c * 3 + 2) * HW] = d;
    if (b0) {
      float* y0p = y0_hwc + hw * 24 + c * 3;
      y0p[0] = ctr; y0p[1] = d; y0p[2] = d;
    }
  }
}

// ---------------------------------------------------------------------------
// K2: attention mat-vec, batch 0 only (reads 255 MB of W_att -> HBM-bound).
// ---------------------------------------------------------------------------
__global__ __launch_bounds__(256) void k_att(
    const float* __restrict__ y0, const float* __restrict__ Watt,
    float* __restrict__ att_acc) {
  int t = threadIdx.x;
  int r0 = blockIdx.x * 128;
  float a0 = 0.f, a1 = 0.f, a2 = 0.f;
  for (int r = 0; r < 128; ++r) {
    float yv = y0[r0 + r];
    const float* wr = Watt + (size_t)(r0 + r) * 648;
    a0 = fmaf(yv, wr[t], a0);
    a1 = fmaf(yv, wr[t + 256], a1);
    if (t < 136) a2 = fmaf(yv, wr[t + 512], a2);
  }
  atomicAdd(att_acc + t, a0);
  atomicAdd(att_acc + t + 256, a1);
  if (t < 136) atomicAdd(att_acc + t + 512, a2);
}

// ---------------------------------------------------------------------------
// K3: depthwise conv2 with attention kernel, LDS-tiled 16x16, SAME pad.
// ---------------------------------------------------------------------------
__global__ __launch_bounds__(256) void k_dw2(
    const float* __restrict__ y_chw, const float* __restrict__ att_acc,
    const float* __restrict__ b_att, float* __restrict__ y2,
    float* __restrict__ ssq) {
  __shared__ float ys[648];
  __shared__ float s[24 * 324];
  int t = threadIdx.x;
  for (int i = t; i < 648; i += 256) ys[i] = att_acc[i] + b_att[i];

  int blk = blockIdx.x;
  int b = blk >> 4;
  int tile = blk & 15;
  int i0 = (tile >> 2) * 16;
  int j0 = (tile & 3) * 16;
  int ty = t >> 4, tx = t & 15;
  const float* yb = y_chw + (size_t)b * 24 * HW;

  for (int idx = t; idx < 24 * 324; idx += 256) {
    int c = idx / 324;
    int pos = idx - c * 324;
    int r = pos / 18, col = pos - r * 18;
    int gr = i0 - 1 + r, gc = j0 - 1 + col;
    bool v = ((unsigned)gr < 64u) && ((unsigned)gc < 64u);
    s[idx] = v ? yb[(size_t)c * HW + gr * 64 + gc] : 0.f;
  }
  __syncthreads();

  float* y2b = y2 + (size_t)b * 72 * HW + (i0 + ty) * 64 + (j0 + tx);
  float local = 0.f;
  for (int c = 0; c < 24; ++c) {
    const float* sc = s + c * 324 + ty * 18 + tx;
    float tap[9];
    #pragma unroll
    for (int di = 0; di < 3; ++di)
      #pragma unroll
      for (int dj = 0; dj < 3; ++dj) tap[di * 3 + dj] = sc[di * 18 + dj];
    #pragma unroll
    for (int m = 0; m < 3; ++m) {
      float acc = 0.f;
      #pragma unroll
      for (int k9 = 0; k9 < 9; ++k9) acc = fmaf(tap[k9], ys[(k9 * 24 + c) * 3 + m], acc);
      y2b[(size_t)(c * 3 + m) * HW] = acc;
      local = fmaf(acc, acc, local);
    }
  }
  #pragma unroll
  for (int off = 32; off; off >>= 1) local += __shfl_down(local, off, 64);
  if ((t & 63) == 0) atomicAdd(ssq, local);
}

// ---------------------------------------------------------------------------
// K4: conv1 3x3 VALID 72->48, LDS-tiled, OUTPUT-CHANNEL-SPLIT.
// 512 threads: group og = t>>8 handles outputs [og*24, og*24+24).
// acc[24]/thread -> ~60 VGPR -> 8 waves/block, 4 blocks/CU = 32 waves/CU.
// ---------------------------------------------------------------------------
__global__ __launch_bounds__(512) void k_conv1(
    const float* __restrict__ y2, const float* __restrict__ W1,
    const float* __restrict__ b1, const float* __restrict__ ssqp,
    float* __restrict__ h1) {
  __shared__ float s[24 * 324];
  int t512 = threadIdx.x;
  int og = t512 >> 8;           // 0 or 1
  int t = t512 & 255;
  int blk = blockIdx.x;
  int b = blk >> 4;
  int tile = blk & 15;
  int i0 = (tile >> 2) * 16; if (i0 > 46) i0 = 46;
  int j0 = (tile & 3) * 16;  if (j0 > 46) j0 = 46;
  int ty = t >> 4, tx = t & 15;

  float acc[24];
  #pragma unroll
  for (int o = 0; o < 24; ++o) acc[o] = 0.f;
  const float* yb = y2 + (size_t)b * 72 * HW;

  for (int c0 = 0; c0 < 72; c0 += 24) {
    __syncthreads();
    for (int idx = t512; idx < 24 * 324; idx += 512) {
      int c = idx / 324;
      int pos = idx - c * 324;
      int r = pos / 18, col = pos - r * 18;
      s[idx] = yb[(size_t)(c0 + c) * HW + (i0 + r) * 64 + (j0 + col)];
    }
    __syncthreads();
    #pragma unroll 2
    for (int c = 0; c < 24; ++c) {
      const float* sc = s + c * 324 + ty * 18 + tx;
      float tap[9];
      #pragma unroll
      for (int di = 0; di < 3; ++di)
        #pragma unroll
        for (int dj = 0; dj < 3; ++dj) tap[di * 3 + dj] = sc[di * 18 + dj];
      #pragma unroll
      for (int k9 = 0; k9 < 9; ++k9) {
        const float* w = W1 + (size_t)(k9 * 72 + c0 + c) * 48 + og * 24;
        float tv = tap[k9];
        #pragma unroll
        for (int o = 0; o < 24; ++o) acc[o] = fmaf(tv, w[o], acc[o]);
      }
    }
  }
  float inv = rsqrtf(fmaxf(ssqp[0], 1e-12f));
  float* hb = h1 + (size_t)b * 48 * 3844 + (size_t)og * 24 * 3844 + (i0 + ty) * 62 + (j0 + tx);
  #pragma unroll
  for (int o = 0; o < 24; ++o) hb[(size_t)o * 3844] = fmaf(acc[o], inv, b1[og * 24 + o]);
}

// ---------------------------------------------------------------------------
// K5: conv_transpose 3x3 (pad-2 correlation, no flip) 48->48, LDS-tiled,
// OUTPUT-CHANNEL-SPLIT like k_conv1. h1[B,48,62,62] -> h2[B,48,64,64].
// ---------------------------------------------------------------------------
__global__ __launch_bounds__(512) void k_convT(
    const float* __restrict__ h1, const float* __restrict__ Wt,
    const float* __restrict__ bt, float* __restrict__ h2) {
  __shared__ float s[24 * 324];
  int t512 = threadIdx.x;
  int og = t512 >> 8;
  int t = t512 & 255;
  int blk = blockIdx.x;
  int b = blk >> 4;
  int tile = blk & 15;
  int i0 = (tile >> 2) * 16;
  int j0 = (tile & 3) * 16;
  int ty = t >> 4, tx = t & 15;

  float acc[24];
  #pragma unroll
  for (int o = 0; o < 24; ++o) acc[o] = 0.f;
  const float* hb = h1 + (size_t)b * 48 * 3844;

  for (int c0 = 0; c0 < 48; c0 += 24) {
    __syncthreads();
    for (int idx = t512; idx < 24 * 324; idx += 512) {
      int c = idx / 324;
      int pos = idx - c * 324;
      int r = pos / 18, col = pos - r * 18;
      int gr = i0 - 2 + r, gc = j0 - 2 + col;
      bool v = ((unsigned)gr < 62u) && ((unsigned)gc < 62u);
      s[idx] = v ? hb[(size_t)(c0 + c) * 3844 + gr * 62 + gc] : 0.f;
    }
    __syncthreads();
    #pragma unroll 2
    for (int c = 0; c < 24; ++c) {
      const float* sc = s + c * 324 + ty * 18 + tx;
      float tap[9];
      #pragma unroll
      for (int di = 0; di < 3; ++di)
        #pragma unroll
        for (int dj = 0; dj < 3; ++dj) tap[di * 3 + dj] = sc[di * 18 + dj];
      #pragma unroll
      for (int k9 = 0; k9 < 9; ++k9) {
        const float* w = Wt + (size_t)(k9 * 48 + c0 + c) * 48 + og * 24;
        float tv = tap[k9];
        #pragma unroll
        for (int o = 0; o < 24; ++o) acc[o] = fmaf(tv, w[o], acc[o]);
      }
    }
  }
  float* ob = h2 + (size_t)b * 48 * HW + (size_t)og * 24 * HW + (i0 + ty) * 64 + (j0 + tx);
  #pragma unroll
  for (int o = 0; o < 24; ++o) ob[(size_t)o * HW] = acc[o] + bt[og * 24 + o];
}

// ---------------------------------------------------------------------------
// K6: 1x1 relu (48->128, W2T rows) -> 1x1 (128->8) -> masked residual.
// ---------------------------------------------------------------------------
__global__ __launch_bounds__(256) void k_head(
    const float* __restrict__ h2, const float* __restrict__ W2T,
    const float* __restrict__ b2, const float* __restrict__ W3,
    const float* __restrict__ b3, const float* __restrict__ x,
    const float* __restrict__ noise, float* __restrict__ x2,
    float* __restrict__ alpha2) {
  int pix = blockIdx.x * 256 + threadIdx.x;
  int b = pix >> 12;
  int hw = pix & 4095;
  float hr[48];
  const float* hb = h2 + (size_t)b * 48 * HW + hw;
  #pragma unroll
  for (int c = 0; c < 48; ++c) hr[c] = hb[(size_t)c * HW];
  float dx[8];
  #pragma unroll
  for (int k = 0; k < 8; ++k) dx[k] = b3[k];
  #pragma unroll 2
  for (int o = 0; o < 128; ++o) {
    float v = b2[o];
    const float* w2 = W2T + o * 48;           // contiguous row
    #pragma unroll
    for (int c = 0; c < 48; ++c) v = fmaf(hr[c], w2[c], v);
    v = fmaxf(v, 0.f);
    const float* w3 = W3 + o * 8;
    #pragma unroll
    for (int k = 0; k < 8; ++k) dx[k] = fmaf(v, w3[k], dx[k]);
  }
  float mask = (noise[pix] <= 0.5f) ? 1.f : 0.f;
  const float* xp = x + (size_t)pix * 8;
  float* xo = x2 + (size_t)pix * 8;
  float a3 = 0.f;
  #pragma unroll
  for (int k = 0; k < 8; ++k) {
    float v = fmaf(dx[k], mask, xp[k]);
    xo[k] = v;
    if (k == 3) a3 = v;
  }
  alpha2[pix] = a3;
}

// ---------------------------------------------------------------------------
// K7: post_life maxpool + alive gating -> d_out
// ---------------------------------------------------------------------------
__global__ __launch_bounds__(256) void k_life(
    const float* __restrict__ x2, const float* __restrict__ alpha2,
    const float* __restrict__ prelife, float* __restrict__ out) {
  int pix = blockIdx.x * 256 + threadIdx.x;
  int hw = pix & 4095;
  int h = hw >> 6, w = hw & 63;
  const float* ab = alpha2 + (size_t)(pix - hw);
  float mx = -1e30f;
  #pragma unroll
  for (int di = -1; di <= 1; ++di) {
    if ((unsigned)(h + di) > 63u) continue;
    #pragma unroll
    for (int dj = -1; dj <= 1; ++dj) {
      if ((unsigned)(w + dj) > 63u) continue;
      mx = fmaxf(mx, ab[(h + di) * 64 + (w + dj)]);
    }
  }
  float life = (mx > 0.1f && prelife[pix] > 0.5f) ? 1.f : 0.f;
  const float* xp = x2 + (size_t)pix * 8;
  float* op = out + (size_t)pix * 8;
  #pragma unroll
  for (int k = 0; k < 8; ++k) op[k] = xp[k] * life;
}

// ---------------------------------------------------------------------------
extern "C" void kernel_launch(void* const* d_in, const int* in_sizes, int n_in,
                              void* d_out, int out_size, void* d_ws, size_t ws_size,
                              hipStream_t stream) {
  const float* x     = (const float*)d_in[0];
  const float* noise = (const float*)d_in[1];
  const float* Watt  = (const float*)d_in[2];
  const float* b_att = (const float*)d_in[3];
  const float* W1    = (const float*)d_in[4];
  const float* b1    = (const float*)d_in[5];
  const float* Wt    = (const float*)d_in[6];
  const float* bt    = (const float*)d_in[7];
  const float* W2    = (const float*)d_in[8];
  const float* b2    = (const float*)d_in[9];
  const float* W3    = (const float*)d_in[10];
  const float* b3    = (const float*)d_in[11];
  float* out = (float*)d_out;

  float* ws = (float*)d_ws;
  size_t o_y   = 0;                       // y_chw [6291456]; later x2+alpha2
  size_t o_y2  = o_y + 6291456;           // y2_chw [18874368]; later h2 [12582912]
  size_t o_h1  = o_y2 + 18874368;         // h1_chw [11808768]
  size_t o_y0  = o_h1 + 11808768;         // y0_hwc [98304]
  size_t o_pre = o_y0 + 98304;            // prelife [262144]
  size_t o_att = o_pre + 262144;          // att_acc[648] + ssq[1]
  size_t o_w2t = o_att + 652;             // W2T [6144]
  float* y_chw   = ws + o_y;
  float* y2_chw  = ws + o_y2;
  float* h2_chw  = ws + o_y2;             // alias: y2 dead after k_conv1
  float* h1_chw  = ws + o_h1;
  float* y0_hwc  = ws + o_y0;
  float* prelife = ws + o_pre;
  float* att_acc = ws + o_att;
  float* ssq     = ws + o_att + 648;
  float* W2T     = ws + o_w2t;
  float* x2      = ws + o_y;              // alias: y dead after k_dw2
  float* alpha2  = ws + o_y + 2097152;

  k_prep<<<1, 256, 0, stream>>>(W2, W2T);
  k_perceive<<<1024, 256, 0, stream>>>(x, y_chw, y0_hwc, prelife, att_acc);
  k_att<<<768, 256, 0, stream>>>(y0_hwc, Watt, att_acc);
  k_dw2<<<1024, 256, 0, stream>>>(y_chw, att_acc, b_att, y2_chw, ssq);
  k_conv1<<<1024, 512, 0, stream>>>(y2_chw, W1, b1, ssq, h1_chw);
  k_convT<<<1024, 512, 0, stream>>>(h1_chw, Wt, bt, h2_chw);
  k_head<<<1024, 256, 0, stream>>>(h2_chw, W2T, b2, W3, b3, x, noise, x2, alpha2);
  k_life<<<1024, 256, 0, stream>>>(x2, alpha2, prelife, out);
}

// Round 4
// 2153.618 us; speedup vs baseline: 1.0387x; 1.0387x over previous
//
#include <hip/hip_runtime.h>

#define NB 64
#define HW 4096           // 64*64

// ---------------------------------------------------------------------------
// K0: transpose W2 [48,128] -> W2T [128,48] (contiguous rows for s_load).
// ---------------------------------------------------------------------------
__global__ __launch_bounds__(256) void k_prep(
    const float* __restrict__ W2, float* __restrict__ W2T) {
  for (int i = threadIdx.x; i < 6144; i += 256) {
    int o = i / 48;
    int c = i - o * 48;
    W2T[i] = W2[c * 128 + o];
  }
}

// ---------------------------------------------------------------------------
// K1: perceive (fixed stencil) + pre_life + zero the atomic accumulators.
// ---------------------------------------------------------------------------
__global__ __launch_bounds__(256) void k_perceive(
    const float* __restrict__ x, float* __restrict__ y_chw,
    float* __restrict__ y0_hwc, float* __restrict__ prelife,
    float* __restrict__ att_zero) {
  int t = threadIdx.x;
  if (blockIdx.x == 0) {
    for (int i = t; i < 649; i += 256) att_zero[i] = 0.f;
  }
  int pix = blockIdx.x * 256 + t;
  int b = pix >> 12;
  int hw = pix & 4095;
  int h = hw >> 6, w = hw & 63;
  const float* xp = x + (size_t)pix * 8;
  bool hm = h > 0, hp = h < 63, wm = w > 0, wp = w < 63;

  float mx = -1e30f;
  #pragma unroll
  for (int di = -1; di <= 1; ++di) {
    if ((unsigned)(h + di) > 63u) continue;
    #pragma unroll
    for (int dj = -1; dj <= 1; ++dj) {
      if ((unsigned)(w + dj) > 63u) continue;
      mx = fmaxf(mx, xp[(di * 64 + dj) * 8 + 3]);
    }
  }
  prelife[pix] = (mx > 0.1f) ? 1.f : 0.f;

  float* yb = y_chw + (size_t)b * 24 * HW + hw;
  bool b0 = (b == 0);
  #pragma unroll
  for (int c = 0; c < 8; ++c) {
    float ctr = xp[c];
    float a00 = (hm && wm) ? xp[(-65) * 8 + c] : 0.f;
    float a02 = (hm && wp) ? xp[(-63) * 8 + c] : 0.f;
    float a20 = (hp && wm) ? xp[(63) * 8 + c] : 0.f;
    float a22 = (hp && wp) ? xp[(65) * 8 + c] : 0.f;
    float d = (a00 + a02 + a20 + a22) * 0.125f;   // dxk == dyk (symmetric)
    yb[(size_t)(c * 3 + 0) * HW] = ctr;
    yb[(size_t)(c * 3 + 1) * HW] = d;
    yb[(size_t)(c * 3 + 2) * HW] = d;
    if (b0) {
      float* y0p = y0_hwc + hw * 24 + c * 3;
      y0p[0] = ctr; y0p[1] = d; y0p[2] = d;
    }
  }
}

// ---------------------------------------------------------------------------
// K2: attention mat-vec, batch 0 only (reads 255 MB of W_att -> HBM-bound).
// ---------------------------------------------------------------------------
__global__ __launch_bounds__(256) void k_att(
    const float* __restrict__ y0, const float* __restrict__ Watt,
    float* __restrict__ att_acc) {
  int t = threadIdx.x;
  int r0 = blockIdx.x * 128;
  float a0 = 0.f, a1 = 0.f, a2 = 0.f;
  for (int r = 0; r < 128; ++r) {
    float yv = y0[r0 + r];
    const float* wr = Watt + (size_t)(r0 + r) * 648;
    a0 = fmaf(yv, wr[t], a0);
    a1 = fmaf(yv, wr[t + 256], a1);
    if (t < 136) a2 = fmaf(yv, wr[t + 512], a2);
  }
  atomicAdd(att_acc + t, a0);
  atomicAdd(att_acc + t + 256, a1);
  if (t < 136) atomicAdd(att_acc + t + 512, a2);
}

// ---------------------------------------------------------------------------
// K3: depthwise conv2 with attention kernel, LDS-tiled 16x16, SAME pad.
// ---------------------------------------------------------------------------
__global__ __launch_bounds__(256) void k_dw2(
    const float* __restrict__ y_chw, const float* __restrict__ att_acc,
    const float* __restrict__ b_att, float* __restrict__ y2,
    float* __restrict__ ssq) {
  __shared__ float ys[648];
  __shared__ float s[24 * 324];
  int t = threadIdx.x;
  for (int i = t; i < 648; i += 256) ys[i] = att_acc[i] + b_att[i];

  int blk = blockIdx.x;
  int b = blk >> 4;
  int tile = blk & 15;
  int i0 = (tile >> 2) * 16;
  int j0 = (tile & 3) * 16;
  int ty = t >> 4, tx = t & 15;
  const float* yb = y_chw + (size_t)b * 24 * HW;

  for (int idx = t; idx < 24 * 324; idx += 256) {
    int c = idx / 324;
    int pos = idx - c * 324;
    int r = pos / 18, col = pos - r * 18;
    int gr = i0 - 1 + r, gc = j0 - 1 + col;
    bool v = ((unsigned)gr < 64u) && ((unsigned)gc < 64u);
    s[idx] = v ? yb[(size_t)c * HW + gr * 64 + gc] : 0.f;
  }
  __syncthreads();

  float* y2b = y2 + (size_t)b * 72 * HW + (i0 + ty) * 64 + (j0 + tx);
  float local = 0.f;
  for (int c = 0; c < 24; ++c) {
    const float* sc = s + c * 324 + ty * 18 + tx;
    float tap[9];
    #pragma unroll
    for (int di = 0; di < 3; ++di)
      #pragma unroll
      for (int dj = 0; dj < 3; ++dj) tap[di * 3 + dj] = sc[di * 18 + dj];
    #pragma unroll
    for (int m = 0; m < 3; ++m) {
      float acc = 0.f;
      #pragma unroll
      for (int k9 = 0; k9 < 9; ++k9) acc = fmaf(tap[k9], ys[(k9 * 24 + c) * 3 + m], acc);
      y2b[(size_t)(c * 3 + m) * HW] = acc;
      local = fmaf(acc, acc, local);
    }
  }
  #pragma unroll
  for (int off = 32; off; off >>= 1) local += __shfl_down(local, off, 64);
  if ((t & 63) == 0) atomicAdd(ssq, local);
}

// ---------------------------------------------------------------------------
// K4: conv1 3x3 VALID 72->48, LDS-tiled, INPUT-CHANNEL-SPLIT.
// 512 threads: group og = t>>8 accumulates input channels og*36..og*36+36
// into a FULL acc[48] (keeps 48 FMAs per tap read), 3 phases of 12 channels
// each (both groups stage their own 12-ch patch: 24*324 floats LDS).
// Final: LDS reduction of the two partial acc[48], og0 stores.
// ---------------------------------------------------------------------------
__global__ __launch_bounds__(512) void k_conv1(
    const float* __restrict__ y2, const float* __restrict__ W1,
    const float* __restrict__ b1, const float* __restrict__ ssqp,
    float* __restrict__ h1) {
  __shared__ float s[24 * 324];
  int t512 = threadIdx.x;
  int og = t512 >> 8;           // 0 or 1 (wave-uniform)
  int t = t512 & 255;
  int blk = blockIdx.x;
  int b = blk >> 4;
  int tile = blk & 15;
  int i0 = (tile >> 2) * 16; if (i0 > 46) i0 = 46;
  int j0 = (tile & 3) * 16;  if (j0 > 46) j0 = 46;
  int ty = t >> 4, tx = t & 15;

  float acc[48];
  #pragma unroll
  for (int o = 0; o < 48; ++o) acc[o] = 0.f;
  const float* yb = y2 + (size_t)b * 72 * HW + (size_t)og * 36 * HW;
  float* sg = s + og * 12 * 324;

  for (int phase = 0; phase < 3; ++phase) {
    __syncthreads();
    for (int idx = t; idx < 12 * 324; idx += 256) {
      int c = idx / 324;
      int pos = idx - c * 324;
      int r = pos / 18, col = pos - r * 18;
      sg[idx] = yb[(size_t)(phase * 12 + c) * HW + (i0 + r) * 64 + (j0 + col)];
    }
    __syncthreads();
    for (int c = 0; c < 12; ++c) {
      const float* sc = sg + c * 324 + ty * 18 + tx;
      float tap[9];
      #pragma unroll
      for (int di = 0; di < 3; ++di)
        #pragma unroll
        for (int dj = 0; dj < 3; ++dj) tap[di * 3 + dj] = sc[di * 18 + dj];
      #pragma unroll
      for (int k9 = 0; k9 < 9; ++k9) {
        const float* w = W1 + (size_t)(k9 * 72 + og * 36 + phase * 12 + c) * 48;
        float tv = tap[k9];
        #pragma unroll
        for (int o = 0; o < 48; ++o) acc[o] = fmaf(tv, w[o], acc[o]);
      }
    }
  }
  // reduce og1 partials into og0, two 24-channel passes through s
  __syncthreads();
  if (og == 1) { for (int o = 0; o < 24; ++o) s[o * 256 + t] = acc[o]; }
  __syncthreads();
  if (og == 0) { for (int o = 0; o < 24; ++o) acc[o] += s[o * 256 + t]; }
  __syncthreads();
  if (og == 1) { for (int o = 0; o < 24; ++o) s[o * 256 + t] = acc[o + 24]; }
  __syncthreads();
  if (og == 0) {
    for (int o = 0; o < 24; ++o) acc[o + 24] += s[o * 256 + t];
    float inv = rsqrtf(fmaxf(ssqp[0], 1e-12f));
    float* hb = h1 + (size_t)b * 48 * 3844 + (i0 + ty) * 62 + (j0 + tx);
    #pragma unroll
    for (int o = 0; o < 48; ++o) hb[(size_t)o * 3844] = fmaf(acc[o], inv, b1[o]);
  }
}

// ---------------------------------------------------------------------------
// K5: conv_transpose 3x3 (pad-2 correlation, no flip) 48->48, LDS-tiled,
// INPUT-CHANNEL-SPLIT (24+24, 2 phases of 12). h1[B,48,62,62]->h2[B,48,64,64].
// ---------------------------------------------------------------------------
__global__ __launch_bounds__(512) void k_convT(
    const float* __restrict__ h1, const float* __restrict__ Wt,
    const float* __restrict__ bt, float* __restrict__ h2) {
  __shared__ float s[24 * 324];
  int t512 = threadIdx.x;
  int og = t512 >> 8;
  int t = t512 & 255;
  int blk = blockIdx.x;
  int b = blk >> 4;
  int tile = blk & 15;
  int i0 = (tile >> 2) * 16;
  int j0 = (tile & 3) * 16;
  int ty = t >> 4, tx = t & 15;

  float acc[48];
  #pragma unroll
  for (int o = 0; o < 48; ++o) acc[o] = 0.f;
  const float* hb = h1 + (size_t)b * 48 * 3844 + (size_t)og * 24 * 3844;
  float* sg = s + og * 12 * 324;

  for (int phase = 0; phase < 2; ++phase) {
    __syncthreads();
    for (int idx = t; idx < 12 * 324; idx += 256) {
      int c = idx / 324;
      int pos = idx - c * 324;
      int r = pos / 18, col = pos - r * 18;
      int gr = i0 - 2 + r, gc = j0 - 2 + col;
      bool v = ((unsigned)gr < 62u) && ((unsigned)gc < 62u);
      sg[idx] = v ? hb[(size_t)(phase * 12 + c) * 3844 + gr * 62 + gc] : 0.f;
    }
    __syncthreads();
    for (int c = 0; c < 12; ++c) {
      const float* sc = sg + c * 324 + ty * 18 + tx;
      float tap[9];
      #pragma unroll
      for (int di = 0; di < 3; ++di)
        #pragma unroll
        for (int dj = 0; dj < 3; ++dj) tap[di * 3 + dj] = sc[di * 18 + dj];
      #pragma unroll
      for (int k9 = 0; k9 < 9; ++k9) {
        const float* w = Wt + (size_t)(k9 * 48 + og * 24 + phase * 12 + c) * 48;
        float tv = tap[k9];
        #pragma unroll
        for (int o = 0; o < 48; ++o) acc[o] = fmaf(tv, w[o], acc[o]);
      }
    }
  }
  __syncthreads();
  if (og == 1) { for (int o = 0; o < 24; ++o) s[o * 256 + t] = acc[o]; }
  __syncthreads();
  if (og == 0) { for (int o = 0; o < 24; ++o) acc[o] += s[o * 256 + t]; }
  __syncthreads();
  if (og == 1) { for (int o = 0; o < 24; ++o) s[o * 256 + t] = acc[o + 24]; }
  __syncthreads();
  if (og == 0) {
    for (int o = 0; o < 24; ++o) acc[o + 24] += s[o * 256 + t];
    float* ob = h2 + (size_t)b * 48 * HW + (i0 + ty) * 64 + (j0 + tx);
    #pragma unroll
    for (int o = 0; o < 48; ++o) ob[(size_t)o * HW] = acc[o] + bt[o];
  }
}

// ---------------------------------------------------------------------------
// K6: 1x1 relu (48->128, W2T rows) -> 1x1 (128->8) -> masked residual.
// ---------------------------------------------------------------------------
__global__ __launch_bounds__(256) void k_head(
    const float* __restrict__ h2, const float* __restrict__ W2T,
    const float* __restrict__ b2, const float* __restrict__ W3,
    const float* __restrict__ b3, const float* __restrict__ x,
    const float* __restrict__ noise, float* __restrict__ x2,
    float* __restrict__ alpha2) {
  int pix = blockIdx.x * 256 + threadIdx.x;
  int b = pix >> 12;
  int hw = pix & 4095;
  float hr[48];
  const float* hb = h2 + (size_t)b * 48 * HW + hw;
  #pragma unroll
  for (int c = 0; c < 48; ++c) hr[c] = hb[(size_t)c * HW];
  float dx[8];
  #pragma unroll
  for (int k = 0; k < 8; ++k) dx[k] = b3[k];
  #pragma unroll 4
  for (int o = 0; o < 128; ++o) {
    float v = b2[o];
    const float* w2 = W2T + o * 48;           // contiguous row
    #pragma unroll
    for (int c = 0; c < 48; ++c) v = fmaf(hr[c], w2[c], v);
    v = fmaxf(v, 0.f);
    const float* w3 = W3 + o * 8;
    #pragma unroll
    for (int k = 0; k < 8; ++k) dx[k] = fmaf(v, w3[k], dx[k]);
  }
  float mask = (noise[pix] <= 0.5f) ? 1.f : 0.f;
  const float* xp = x + (size_t)pix * 8;
  float* xo = x2 + (size_t)pix * 8;
  float a3 = 0.f;
  #pragma unroll
  for (int k = 0; k < 8; ++k) {
    float v = fmaf(dx[k], mask, xp[k]);
    xo[k] = v;
    if (k == 3) a3 = v;
  }
  alpha2[pix] = a3;
}

// ---------------------------------------------------------------------------
// K7: post_life maxpool + alive gating -> d_out
// ---------------------------------------------------------------------------
__global__ __launch_bounds__(256) void k_life(
    const float* __restrict__ x2, const float* __restrict__ alpha2,
    const float* __restrict__ prelife, float* __restrict__ out) {
  int pix = blockIdx.x * 256 + threadIdx.x;
  int hw = pix & 4095;
  int h = hw >> 6, w = hw & 63;
  const float* ab = alpha2 + (size_t)(pix - hw);
  float mx = -1e30f;
  #pragma unroll
  for (int di = -1; di <= 1; ++di) {
    if ((unsigned)(h + di) > 63u) continue;
    #pragma unroll
    for (int dj = -1; dj <= 1; ++dj) {
      if ((unsigned)(w + dj) > 63u) continue;
      mx = fmaxf(mx, ab[(h + di) * 64 + (w + dj)]);
    }
  }
  float life = (mx > 0.1f && prelife[pix] > 0.5f) ? 1.f : 0.f;
  const float* xp = x2 + (size_t)pix * 8;
  float* op = out + (size_t)pix * 8;
  #pragma unroll
  for (int k = 0; k < 8; ++k) op[k] = xp[k] * life;
}

// ---------------------------------------------------------------------------
extern "C" void kernel_launch(void* const* d_in, const int* in_sizes, int n_in,
                              void* d_out, int out_size, void* d_ws, size_t ws_size,
                              hipStream_t stream) {
  const float* x     = (const float*)d_in[0];
  const float* noise = (const float*)d_in[1];
  const float* Watt  = (const float*)d_in[2];
  const float* b_att = (const float*)d_in[3];
  const float* W1    = (const float*)d_in[4];
  const float* b1    = (const float*)d_in[5];
  const float* Wt    = (const float*)d_in[6];
  const float* bt    = (const float*)d_in[7];
  const float* W2    = (const float*)d_in[8];
  const float* b2    = (const float*)d_in[9];
  const float* W3    = (const float*)d_in[10];
  const float* b3    = (const float*)d_in[11];
  float* out = (float*)d_out;

  float* ws = (float*)d_ws;
  size_t o_y   = 0;                       // y_chw [6291456]; later x2+alpha2
  size_t o_y2  = o_y + 6291456;           // y2_chw [18874368]; later h2 [12582912]
  size_t o_h1  = o_y2 + 18874368;         // h1_chw [11808768]
  size_t o_y0  = o_h1 + 11808768;         // y0_hwc [98304]
  size_t o_pre = o_y0 + 98304;            // prelife [262144]
  size_t o_att = o_pre + 262144;          // att_acc[648] + ssq[1]
  size_t o_w2t = o_att + 652;             // W2T [6144]
  float* y_chw   = ws + o_y;
  float* y2_chw  = ws + o_y2;
  float* h2_chw  = ws + o_y2;             // alias: y2 dead after k_conv1
  float* h1_chw  = ws + o_h1;
  float* y0_hwc  = ws + o_y0;
  float* prelife = ws + o_pre;
  float* att_acc = ws + o_att;
  float* ssq     = ws + o_att + 648;
  float* W2T     = ws + o_w2t;
  float* x2      = ws + o_y;              // alias: y dead after k_dw2
  float* alpha2  = ws + o_y + 2097152;

  k_prep<<<1, 256, 0, stream>>>(W2, W2T);
  k_perceive<<<1024, 256, 0, stream>>>(x, y_chw, y0_hwc, prelife, att_acc);
  k_att<<<768, 256, 0, stream>>>(y0_hwc, Watt, att_acc);
  k_dw2<<<1024, 256, 0, stream>>>(y_chw, att_acc, b_att, y2_chw, ssq);
  k_conv1<<<1024, 512, 0, stream>>>(y2_chw, W1, b1, ssq, h1_chw);
  k_convT<<<1024, 512, 0, stream>>>(h1_chw, Wt, bt, h2_chw);
  k_head<<<1024, 256, 0, stream>>>(h2_chw, W2T, b2, W3, b3, x, noise, x2, alpha2);
  k_life<<<1024, 256, 0, stream>>>(x2, alpha2, prelife, out);
}

// Round 5
// 995.417 us; speedup vs baseline: 2.2472x; 2.1635x over previous
//
#include <hip/hip_runtime.h>

#define NB 64
#define HW 4096           // 64*64

// ---------------------------------------------------------------------------
// K0: transpose W2 [48,128] -> W2T [128,48] (contiguous rows for s_load).
// ---------------------------------------------------------------------------
__global__ __launch_bounds__(256) void k_prep(
    const float* __restrict__ W2, float* __restrict__ W2T) {
  for (int i = threadIdx.x; i < 6144; i += 256) {
    int o = i / 48;
    int c = i - o * 48;
    W2T[i] = W2[c * 128 + o];
  }
}

// ---------------------------------------------------------------------------
// K1: perceive (fixed stencil) + pre_life + zero the atomic accumulators.
// ---------------------------------------------------------------------------
__global__ __launch_bounds__(256) void k_perceive(
    const float* __restrict__ x, float* __restrict__ y_chw,
    float* __restrict__ y0_hwc, float* __restrict__ prelife,
    float* __restrict__ att_zero) {
  int t = threadIdx.x;
  if (blockIdx.x == 0) {
    for (int i = t; i < 649; i += 256) att_zero[i] = 0.f;
  }
  int pix = blockIdx.x * 256 + t;
  int b = pix >> 12;
  int hw = pix & 4095;
  int h = hw >> 6, w = hw & 63;
  const float* xp = x + (size_t)pix * 8;
  bool hm = h > 0, hp = h < 63, wm = w > 0, wp = w < 63;

  float mx = -1e30f;
  #pragma unroll
  for (int di = -1; di <= 1; ++di) {
    if ((unsigned)(h + di) > 63u) continue;
    #pragma unroll
    for (int dj = -1; dj <= 1; ++dj) {
      if ((unsigned)(w + dj) > 63u) continue;
      mx = fmaxf(mx, xp[(di * 64 + dj) * 8 + 3]);
    }
  }
  prelife[pix] = (mx > 0.1f) ? 1.f : 0.f;

  float* yb = y_chw + (size_t)b * 24 * HW + hw;
  bool b0 = (b == 0);
  #pragma unroll
  for (int c = 0; c < 8; ++c) {
    float ctr = xp[c];
    float a00 = (hm && wm) ? xp[(-65) * 8 + c] : 0.f;
    float a02 = (hm && wp) ? xp[(-63) * 8 + c] : 0.f;
    float a20 = (hp && wm) ? xp[(63) * 8 + c] : 0.f;
    float a22 = (hp && wp) ? xp[(65) * 8 + c] : 0.f;
    float d = (a00 + a02 + a20 + a22) * 0.125f;   // dxk == dyk (symmetric)
    yb[(size_t)(c * 3 + 0) * HW] = ctr;
    yb[(size_t)(c * 3 + 1) * HW] = d;
    yb[(size_t)(c * 3 + 2) * HW] = d;
    if (b0) {
      float* y0p = y0_hwc + hw * 24 + c * 3;
      y0p[0] = ctr; y0p[1] = d; y0p[2] = d;
    }
  }
}

// ---------------------------------------------------------------------------
// K2: attention mat-vec, batch 0 only (reads 255 MB of W_att -> HBM-bound).
// ---------------------------------------------------------------------------
__global__ __launch_bounds__(256) void k_att(
    const float* __restrict__ y0, const float* __restrict__ Watt,
    float* __restrict__ att_acc) {
  int t = threadIdx.x;
  int r0 = blockIdx.x * 128;
  float a0 = 0.f, a1 = 0.f, a2 = 0.f;
  for (int r = 0; r < 128; ++r) {
    float yv = y0[r0 + r];
    const float* wr = Watt + (size_t)(r0 + r) * 648;
    a0 = fmaf(yv, wr[t], a0);
    a1 = fmaf(yv, wr[t + 256], a1);
    if (t < 136) a2 = fmaf(yv, wr[t + 512], a2);
  }
  atomicAdd(att_acc + t, a0);
  atomicAdd(att_acc + t + 256, a1);
  if (t < 136) atomicAdd(att_acc + t + 512, a2);
}

// ---------------------------------------------------------------------------
// K3: depthwise conv2 with attention kernel, LDS-tiled 16x16, SAME pad.
// ---------------------------------------------------------------------------
__global__ __launch_bounds__(256) void k_dw2(
    const float* __restrict__ y_chw, const float* __restrict__ att_acc,
    const float* __restrict__ b_att, float* __restrict__ y2,
    float* __restrict__ ssq) {
  __shared__ float ys[648];
  __shared__ float s[24 * 324];
  int t = threadIdx.x;
  for (int i = t; i < 648; i += 256) ys[i] = att_acc[i] + b_att[i];

  int blk = blockIdx.x;
  int b = blk >> 4;
  int tile = blk & 15;
  int i0 = (tile >> 2) * 16;
  int j0 = (tile & 3) * 16;
  int ty = t >> 4, tx = t & 15;
  const float* yb = y_chw + (size_t)b * 24 * HW;

  for (int idx = t; idx < 24 * 324; idx += 256) {
    int c = idx / 324;
    int pos = idx - c * 324;
    int r = pos / 18, col = pos - r * 18;
    int gr = i0 - 1 + r, gc = j0 - 1 + col;
    bool v = ((unsigned)gr < 64u) && ((unsigned)gc < 64u);
    s[idx] = v ? yb[(size_t)c * HW + gr * 64 + gc] : 0.f;
  }
  __syncthreads();

  float* y2b = y2 + (size_t)b * 72 * HW + (i0 + ty) * 64 + (j0 + tx);
  float local = 0.f;
  for (int c = 0; c < 24; ++c) {
    const float* sc = s + c * 324 + ty * 18 + tx;
    float tap[9];
    #pragma unroll
    for (int di = 0; di < 3; ++di)
      #pragma unroll
      for (int dj = 0; dj < 3; ++dj) tap[di * 3 + dj] = sc[di * 18 + dj];
    #pragma unroll
    for (int m = 0; m < 3; ++m) {
      float acc = 0.f;
      #pragma unroll
      for (int k9 = 0; k9 < 9; ++k9) acc = fmaf(tap[k9], ys[(k9 * 24 + c) * 3 + m], acc);
      y2b[(size_t)(c * 3 + m) * HW] = acc;
      local = fmaf(acc, acc, local);
    }
  }
  #pragma unroll
  for (int off = 32; off; off >>= 1) local += __shfl_down(local, off, 64);
  if ((t & 63) == 0) atomicAdd(ssq, local);
}

// ---------------------------------------------------------------------------
// K4: conv1 3x3 VALID 72->48, LDS-tiled, OUTPUT-CHANNEL-SPLIT with
// WAVE-UNIFORM og via readfirstlane (keeps weight loads on the s_load path;
// R3/R4 regression root cause was divergent-og weight addressing -> per-lane
// vector weight loads). 512 threads = 8 waves -> 32 waves/CU at 1024 blocks.
// Group og handles outputs [og*24, og*24+24) over ALL 72 input channels.
// ---------------------------------------------------------------------------
__global__ __launch_bounds__(512) void k_conv1(
    const float* __restrict__ y2, const float* __restrict__ W1,
    const float* __restrict__ b1, const float* __restrict__ ssqp,
    float* __restrict__ h1) {
  __shared__ float s[24 * 324];
  int t512 = threadIdx.x;
  int og = __builtin_amdgcn_readfirstlane(t512 >> 8);   // wave-uniform 0/1
  int t = t512 & 255;
  int blk = blockIdx.x;
  int b = blk >> 4;
  int tile = blk & 15;
  int i0 = (tile >> 2) * 16; if (i0 > 46) i0 = 46;
  int j0 = (tile & 3) * 16;  if (j0 > 46) j0 = 46;
  int ty = t >> 4, tx = t & 15;

  float acc[24];
  #pragma unroll
  for (int o = 0; o < 24; ++o) acc[o] = 0.f;
  const float* yb = y2 + (size_t)b * 72 * HW;

  for (int c0 = 0; c0 < 72; c0 += 24) {
    __syncthreads();
    for (int idx = t512; idx < 24 * 324; idx += 512) {
      int c = idx / 324;
      int pos = idx - c * 324;
      int r = pos / 18, col = pos - r * 18;
      s[idx] = yb[(size_t)(c0 + c) * HW + (i0 + r) * 64 + (j0 + col)];
    }
    __syncthreads();
    for (int c = 0; c < 24; ++c) {
      const float* sc = s + c * 324 + ty * 18 + tx;
      float tap[9];
      #pragma unroll
      for (int di = 0; di < 3; ++di)
        #pragma unroll
        for (int dj = 0; dj < 3; ++dj) tap[di * 3 + dj] = sc[di * 18 + dj];
      #pragma unroll
      for (int k9 = 0; k9 < 9; ++k9) {
        const float* w = W1 + (size_t)(k9 * 72 + c0 + c) * 48 + og * 24;  // SGPR
        float tv = tap[k9];
        #pragma unroll
        for (int o = 0; o < 24; ++o) acc[o] = fmaf(tv, w[o], acc[o]);
      }
    }
  }
  float inv = rsqrtf(fmaxf(ssqp[0], 1e-12f));
  float* hb = h1 + (size_t)b * 48 * 3844 + (size_t)og * 24 * 3844
            + (i0 + ty) * 62 + (j0 + tx);
  #pragma unroll
  for (int o = 0; o < 24; ++o) hb[(size_t)o * 3844] = fmaf(acc[o], inv, b1[og * 24 + o]);
}

// ---------------------------------------------------------------------------
// K5: conv_transpose 3x3 (pad-2 correlation, no flip) 48->48, LDS-tiled,
// OUTPUT-CHANNEL-SPLIT with wave-uniform og (same fix as k_conv1).
// h1[B,48,62,62] -> h2[B,48,64,64].
// ---------------------------------------------------------------------------
__global__ __launch_bounds__(512) void k_convT(
    const float* __restrict__ h1, const float* __restrict__ Wt,
    const float* __restrict__ bt, float* __restrict__ h2) {
  __shared__ float s[24 * 324];
  int t512 = threadIdx.x;
  int og = __builtin_amdgcn_readfirstlane(t512 >> 8);   // wave-uniform 0/1
  int t = t512 & 255;
  int blk = blockIdx.x;
  int b = blk >> 4;
  int tile = blk & 15;
  int i0 = (tile >> 2) * 16;
  int j0 = (tile & 3) * 16;
  int ty = t >> 4, tx = t & 15;

  float acc[24];
  #pragma unroll
  for (int o = 0; o < 24; ++o) acc[o] = 0.f;
  const float* hb = h1 + (size_t)b * 48 * 3844;

  for (int c0 = 0; c0 < 48; c0 += 24) {
    __syncthreads();
    for (int idx = t512; idx < 24 * 324; idx += 512) {
      int c = idx / 324;
      int pos = idx - c * 324;
      int r = pos / 18, col = pos - r * 18;
      int gr = i0 - 2 + r, gc = j0 - 2 + col;
      bool v = ((unsigned)gr < 62u) && ((unsigned)gc < 62u);
      s[idx] = v ? hb[(size_t)(c0 + c) * 3844 + gr * 62 + gc] : 0.f;
    }
    __syncthreads();
    for (int c = 0; c < 24; ++c) {
      const float* sc = s + c * 324 + ty * 18 + tx;
      float tap[9];
      #pragma unroll
      for (int di = 0; di < 3; ++di)
        #pragma unroll
        for (int dj = 0; dj < 3; ++dj) tap[di * 3 + dj] = sc[di * 18 + dj];
      #pragma unroll
      for (int k9 = 0; k9 < 9; ++k9) {
        const float* w = Wt + (size_t)(k9 * 48 + c0 + c) * 48 + og * 24;  // SGPR
        float tv = tap[k9];
        #pragma unroll
        for (int o = 0; o < 24; ++o) acc[o] = fmaf(tv, w[o], acc[o]);
      }
    }
  }
  float* ob = h2 + (size_t)b * 48 * HW + (size_t)og * 24 * HW
            + (i0 + ty) * 64 + (j0 + tx);
  #pragma unroll
  for (int o = 0; o < 24; ++o) ob[(size_t)o * HW] = acc[o] + bt[og * 24 + o];
}

// ---------------------------------------------------------------------------
// K6: 1x1 relu (48->128, W2T rows) -> 1x1 (128->8) -> masked residual.
// ---------------------------------------------------------------------------
__global__ __launch_bounds__(256) void k_head(
    const float* __restrict__ h2, const float* __restrict__ W2T,
    const float* __restrict__ b2, const float* __restrict__ W3,
    const float* __restrict__ b3, const float* __restrict__ x,
    const float* __restrict__ noise, float* __restrict__ x2,
    float* __restrict__ alpha2) {
  int pix = blockIdx.x * 256 + threadIdx.x;
  int b = pix >> 12;
  int hw = pix & 4095;
  float hr[48];
  const float* hb = h2 + (size_t)b * 48 * HW + hw;
  #pragma unroll
  for (int c = 0; c < 48; ++c) hr[c] = hb[(size_t)c * HW];
  float dx[8];
  #pragma unroll
  for (int k = 0; k < 8; ++k) dx[k] = b3[k];
  #pragma unroll 4
  for (int o = 0; o < 128; ++o) {
    float v = b2[o];
    const float* w2 = W2T + o * 48;           // contiguous row -> s_load
    #pragma unroll
    for (int c = 0; c < 48; ++c) v = fmaf(hr[c], w2[c], v);
    v = fmaxf(v, 0.f);
    const float* w3 = W3 + o * 8;
    #pragma unroll
    for (int k = 0; k < 8; ++k) dx[k] = fmaf(v, w3[k], dx[k]);
  }
  float mask = (noise[pix] <= 0.5f) ? 1.f : 0.f;
  const float* xp = x + (size_t)pix * 8;
  float* xo = x2 + (size_t)pix * 8;
  float a3 = 0.f;
  #pragma unroll
  for (int k = 0; k < 8; ++k) {
    float v = fmaf(dx[k], mask, xp[k]);
    xo[k] = v;
    if (k == 3) a3 = v;
  }
  alpha2[pix] = a3;
}

// ---------------------------------------------------------------------------
// K7: post_life maxpool + alive gating -> d_out
// ---------------------------------------------------------------------------
__global__ __launch_bounds__(256) void k_life(
    const float* __restrict__ x2, const float* __restrict__ alpha2,
    const float* __restrict__ prelife, float* __restrict__ out) {
  int pix = blockIdx.x * 256 + threadIdx.x;
  int hw = pix & 4095;
  int h = hw >> 6, w = hw & 63;
  const float* ab = alpha2 + (size_t)(pix - hw);
  float mx = -1e30f;
  #pragma unroll
  for (int di = -1; di <= 1; ++di) {
    if ((unsigned)(h + di) > 63u) continue;
    #pragma unroll
    for (int dj = -1; dj <= 1; ++dj) {
      if ((unsigned)(w + dj) > 63u) continue;
      mx = fmaxf(mx, ab[(h + di) * 64 + (w + dj)]);
    }
  }
  float life = (mx > 0.1f && prelife[pix] > 0.5f) ? 1.f : 0.f;
  const float* xp = x2 + (size_t)pix * 8;
  float* op = out + (size_t)pix * 8;
  #pragma unroll
  for (int k = 0; k < 8; ++k) op[k] = xp[k] * life;
}

// ---------------------------------------------------------------------------
extern "C" void kernel_launch(void* const* d_in, const int* in_sizes, int n_in,
                              void* d_out, int out_size, void* d_ws, size_t ws_size,
                              hipStream_t stream) {
  const float* x     = (const float*)d_in[0];
  const float* noise = (const float*)d_in[1];
  const float* Watt  = (const float*)d_in[2];
  const float* b_att = (const float*)d_in[3];
  const float* W1    = (const float*)d_in[4];
  const float* b1    = (const float*)d_in[5];
  const float* Wt    = (const float*)d_in[6];
  const float* bt    = (const float*)d_in[7];
  const float* W2    = (const float*)d_in[8];
  const float* b2    = (const float*)d_in[9];
  const float* W3    = (const float*)d_in[10];
  const float* b3    = (const float*)d_in[11];
  float* out = (float*)d_out;

  float* ws = (float*)d_ws;
  size_t o_y   = 0;                       // y_chw [6291456]; later x2+alpha2
  size_t o_y2  = o_y + 6291456;           // y2_chw [18874368]; later h2 [12582912]
  size_t o_h1  = o_y2 + 18874368;         // h1_chw [11808768]
  size_t o_y0  = o_h1 + 11808768;         // y0_hwc [98304]
  size_t o_pre = o_y0 + 98304;            // prelife [262144]
  size_t o_att = o_pre + 262144;          // att_acc[648] + ssq[1]
  size_t o_w2t = o_att + 652;             // W2T [6144]
  float* y_chw   = ws + o_y;
  float* y2_chw  = ws + o_y2;
  float* h2_chw  = ws + o_y2;             // alias: y2 dead after k_conv1
  float* h1_chw  = ws + o_h1;
  float* y0_hwc  = ws + o_y0;
  float* prelife = ws + o_pre;
  float* att_acc = ws + o_att;
  float* ssq     = ws + o_att + 648;
  float* W2T     = ws + o_w2t;
  float* x2      = ws + o_y;              // alias: y dead after k_dw2
  float* alpha2  = ws + o_y + 2097152;

  k_prep<<<1, 256, 0, stream>>>(W2, W2T);
  k_perceive<<<1024, 256, 0, stream>>>(x, y_chw, y0_hwc, prelife, att_acc);
  k_att<<<768, 256, 0, stream>>>(y0_hwc, Watt, att_acc);
  k_dw2<<<1024, 256, 0, stream>>>(y_chw, att_acc, b_att, y2_chw, ssq);
  k_conv1<<<1024, 512, 0, stream>>>(y2_chw, W1, b1, ssq, h1_chw);
  k_convT<<<1024, 512, 0, stream>>>(h1_chw, Wt, bt, h2_chw);
  k_head<<<1024, 256, 0, stream>>>(h2_chw, W2T, b2, W3, b3, x, noise, x2, alpha2);
  k_life<<<1024, 256, 0, stream>>>(x2, alpha2, prelife, out);
}

// Round 6
// 957.261 us; speedup vs baseline: 2.3368x; 1.0399x over previous
//
#include <hip/hip_runtime.h>

#define NB 64
#define HW 4096           // 64*64

// ---------------------------------------------------------------------------
// K0: transpose W2 [48,128] -> W2T [128,48] (contiguous rows for s_load).
// ---------------------------------------------------------------------------
__global__ __launch_bounds__(256) void k_prep(
    const float* __restrict__ W2, float* __restrict__ W2T) {
  for (int i = threadIdx.x; i < 6144; i += 256) {
    int o = i / 48;
    int c = i - o * 48;
    W2T[i] = W2[c * 128 + o];
  }
}

// ---------------------------------------------------------------------------
// K1: perceive (fixed stencil) + pre_life + zero the atomic accumulators.
// ---------------------------------------------------------------------------
__global__ __launch_bounds__(256) void k_perceive(
    const float* __restrict__ x, float* __restrict__ y_chw,
    float* __restrict__ y0_hwc, float* __restrict__ prelife,
    float* __restrict__ att_zero) {
  int t = threadIdx.x;
  if (blockIdx.x == 0) {
    for (int i = t; i < 649; i += 256) att_zero[i] = 0.f;
  }
  int pix = blockIdx.x * 256 + t;
  int b = pix >> 12;
  int hw = pix & 4095;
  int h = hw >> 6, w = hw & 63;
  const float* xp = x + (size_t)pix * 8;
  bool hm = h > 0, hp = h < 63, wm = w > 0, wp = w < 63;

  float mx = -1e30f;
  #pragma unroll
  for (int di = -1; di <= 1; ++di) {
    if ((unsigned)(h + di) > 63u) continue;
    #pragma unroll
    for (int dj = -1; dj <= 1; ++dj) {
      if ((unsigned)(w + dj) > 63u) continue;
      mx = fmaxf(mx, xp[(di * 64 + dj) * 8 + 3]);
    }
  }
  prelife[pix] = (mx > 0.1f) ? 1.f : 0.f;

  float* yb = y_chw + (size_t)b * 24 * HW + hw;
  bool b0 = (b == 0);
  #pragma unroll
  for (int c = 0; c < 8; ++c) {
    float ctr = xp[c];
    float a00 = (hm && wm) ? xp[(-65) * 8 + c] : 0.f;
    float a02 = (hm && wp) ? xp[(-63) * 8 + c] : 0.f;
    float a20 = (hp && wm) ? xp[(63) * 8 + c] : 0.f;
    float a22 = (hp && wp) ? xp[(65) * 8 + c] : 0.f;
    float d = (a00 + a02 + a20 + a22) * 0.125f;   // dxk == dyk (symmetric)
    yb[(size_t)(c * 3 + 0) * HW] = ctr;
    yb[(size_t)(c * 3 + 1) * HW] = d;
    yb[(size_t)(c * 3 + 2) * HW] = d;
    if (b0) {
      float* y0p = y0_hwc + hw * 24 + c * 3;
      y0p[0] = ctr; y0p[1] = d; y0p[2] = d;
    }
  }
}

// ---------------------------------------------------------------------------
// K2: attention mat-vec, batch 0 only (reads 255 MB of W_att -> HBM-bound).
// ---------------------------------------------------------------------------
__global__ __launch_bounds__(256) void k_att(
    const float* __restrict__ y0, const float* __restrict__ Watt,
    float* __restrict__ att_acc) {
  int t = threadIdx.x;
  int r0 = blockIdx.x * 128;
  float a0 = 0.f, a1 = 0.f, a2 = 0.f;
  for (int r = 0; r < 128; ++r) {
    float yv = y0[r0 + r];
    const float* wr = Watt + (size_t)(r0 + r) * 648;
    a0 = fmaf(yv, wr[t], a0);
    a1 = fmaf(yv, wr[t + 256], a1);
    if (t < 136) a2 = fmaf(yv, wr[t + 512], a2);
  }
  atomicAdd(att_acc + t, a0);
  atomicAdd(att_acc + t + 256, a1);
  if (t < 136) atomicAdd(att_acc + t + 512, a2);
}

// ---------------------------------------------------------------------------
// K3: depthwise conv2 with attention kernel, LDS-tiled 16x16, SAME pad.
// ---------------------------------------------------------------------------
__global__ __launch_bounds__(256) void k_dw2(
    const float* __restrict__ y_chw, const float* __restrict__ att_acc,
    const float* __restrict__ b_att, float* __restrict__ y2,
    float* __restrict__ ssq) {
  __shared__ float ys[648];
  __shared__ float s[24 * 324];
  int t = threadIdx.x;
  for (int i = t; i < 648; i += 256) ys[i] = att_acc[i] + b_att[i];

  int blk = blockIdx.x;
  int b = blk >> 4;
  int tile = blk & 15;
  int i0 = (tile >> 2) * 16;
  int j0 = (tile & 3) * 16;
  int ty = t >> 4, tx = t & 15;
  const float* yb = y_chw + (size_t)b * 24 * HW;

  for (int idx = t; idx < 24 * 324; idx += 256) {
    int c = idx / 324;
    int pos = idx - c * 324;
    int r = pos / 18, col = pos - r * 18;
    int gr = i0 - 1 + r, gc = j0 - 1 + col;
    bool v = ((unsigned)gr < 64u) && ((unsigned)gc < 64u);
    s[idx] = v ? yb[(size_t)c * HW + gr * 64 + gc] : 0.f;
  }
  __syncthreads();

  float* y2b = y2 + (size_t)b * 72 * HW + (i0 + ty) * 64 + (j0 + tx);
  float local = 0.f;
  for (int c = 0; c < 24; ++c) {
    const float* sc = s + c * 324 + ty * 18 + tx;
    float tap[9];
    #pragma unroll
    for (int di = 0; di < 3; ++di)
      #pragma unroll
      for (int dj = 0; dj < 3; ++dj) tap[di * 3 + dj] = sc[di * 18 + dj];
    #pragma unroll
    for (int m = 0; m < 3; ++m) {
      float acc = 0.f;
      #pragma unroll
      for (int k9 = 0; k9 < 9; ++k9) acc = fmaf(tap[k9], ys[(k9 * 24 + c) * 3 + m], acc);
      y2b[(size_t)(c * 3 + m) * HW] = acc;
      local = fmaf(acc, acc, local);
    }
  }
  #pragma unroll
  for (int off = 32; off; off >>= 1) local += __shfl_down(local, off, 64);
  if ((t & 63) == 0) atomicAdd(ssq, local);
}

// ---------------------------------------------------------------------------
// K4: conv1 3x3 VALID 72->48, LDS-tiled, og-split + P=2 pixel blocking.
// 256 threads: og = t>>7 (waves 0-1 vs 2-3, wave-uniform) picks output
// channels [og*24, og*24+24); sub = t&127 -> (ty in 0..7, tx in 0..15);
// each thread computes rows ty and ty+8. Per (c,k9): 24 s_load floats feed
// 48 FMAs (2x the R5 ratio -> half the weight-latency stalls).
// ---------------------------------------------------------------------------
__global__ __launch_bounds__(256, 4) void k_conv1(
    const float* __restrict__ y2, const float* __restrict__ W1,
    const float* __restrict__ b1, const float* __restrict__ ssqp,
    float* __restrict__ h1) {
  __shared__ float s[24 * 324];
  int t = threadIdx.x;
  int og = __builtin_amdgcn_readfirstlane(t >> 7);      // wave-uniform 0/1
  int sub = t & 127;
  int ty = sub >> 4, tx = sub & 15;                     // ty 0..7
  int blk = blockIdx.x;
  int b = blk >> 4;
  int tile = blk & 15;
  int i0 = (tile >> 2) * 16; if (i0 > 46) i0 = 46;
  int j0 = (tile & 3) * 16;  if (j0 > 46) j0 = 46;

  float acc0[24], acc1[24];
  #pragma unroll
  for (int o = 0; o < 24; ++o) { acc0[o] = 0.f; acc1[o] = 0.f; }
  const float* yb = y2 + (size_t)b * 72 * HW;

  for (int c0 = 0; c0 < 72; c0 += 24) {
    __syncthreads();
    for (int idx = t; idx < 24 * 324; idx += 256) {
      int c = idx / 324;
      int pos = idx - c * 324;
      int r = pos / 18, col = pos - r * 18;
      s[idx] = yb[(size_t)(c0 + c) * HW + (i0 + r) * 64 + (j0 + col)];
    }
    __syncthreads();
    for (int c = 0; c < 24; ++c) {
      const float* sc = s + c * 324 + ty * 18 + tx;
      float tap0[9], tap1[9];
      #pragma unroll
      for (int di = 0; di < 3; ++di)
        #pragma unroll
        for (int dj = 0; dj < 3; ++dj) {
          tap0[di * 3 + dj] = sc[di * 18 + dj];
          tap1[di * 3 + dj] = sc[(di + 8) * 18 + dj];
        }
      #pragma unroll
      for (int k9 = 0; k9 < 9; ++k9) {
        const float* w = W1 + (size_t)(k9 * 72 + c0 + c) * 48 + og * 24;  // SGPR
        float tv0 = tap0[k9], tv1 = tap1[k9];
        #pragma unroll
        for (int o = 0; o < 24; ++o) {
          acc0[o] = fmaf(tv0, w[o], acc0[o]);
          acc1[o] = fmaf(tv1, w[o], acc1[o]);
        }
      }
    }
  }
  float inv = rsqrtf(fmaxf(ssqp[0], 1e-12f));
  float* hb = h1 + (size_t)b * 48 * 3844 + (size_t)og * 24 * 3844
            + (i0 + ty) * 62 + (j0 + tx);
  #pragma unroll
  for (int o = 0; o < 24; ++o) {
    float bo = b1[og * 24 + o];
    hb[(size_t)o * 3844] = fmaf(acc0[o], inv, bo);
    hb[(size_t)o * 3844 + 8 * 62] = fmaf(acc1[o], inv, bo);
  }
}

// ---------------------------------------------------------------------------
// K5: conv_transpose 3x3 (pad-2 correlation, no flip) 48->48, LDS-tiled,
// og-split + P=2 (same scheme as k_conv1). h1[B,48,62,62]->h2[B,48,64,64].
// ---------------------------------------------------------------------------
__global__ __launch_bounds__(256, 4) void k_convT(
    const float* __restrict__ h1, const float* __restrict__ Wt,
    const float* __restrict__ bt, float* __restrict__ h2) {
  __shared__ float s[24 * 324];
  int t = threadIdx.x;
  int og = __builtin_amdgcn_readfirstlane(t >> 7);      // wave-uniform 0/1
  int sub = t & 127;
  int ty = sub >> 4, tx = sub & 15;
  int blk = blockIdx.x;
  int b = blk >> 4;
  int tile = blk & 15;
  int i0 = (tile >> 2) * 16;
  int j0 = (tile & 3) * 16;

  float acc0[24], acc1[24];
  #pragma unroll
  for (int o = 0; o < 24; ++o) { acc0[o] = 0.f; acc1[o] = 0.f; }
  const float* hb = h1 + (size_t)b * 48 * 3844;

  for (int c0 = 0; c0 < 48; c0 += 24) {
    __syncthreads();
    for (int idx = t; idx < 24 * 324; idx += 256) {
      int c = idx / 324;
      int pos = idx - c * 324;
      int r = pos / 18, col = pos - r * 18;
      int gr = i0 - 2 + r, gc = j0 - 2 + col;
      bool v = ((unsigned)gr < 62u) && ((unsigned)gc < 62u);
      s[idx] = v ? hb[(size_t)(c0 + c) * 3844 + gr * 62 + gc] : 0.f;
    }
    __syncthreads();
    for (int c = 0; c < 24; ++c) {
      const float* sc = s + c * 324 + ty * 18 + tx;
      float tap0[9], tap1[9];
      #pragma unroll
      for (int di = 0; di < 3; ++di)
        #pragma unroll
        for (int dj = 0; dj < 3; ++dj) {
          tap0[di * 3 + dj] = sc[di * 18 + dj];
          tap1[di * 3 + dj] = sc[(di + 8) * 18 + dj];
        }
      #pragma unroll
      for (int k9 = 0; k9 < 9; ++k9) {
        const float* w = Wt + (size_t)(k9 * 48 + c0 + c) * 48 + og * 24;  // SGPR
        float tv0 = tap0[k9], tv1 = tap1[k9];
        #pragma unroll
        for (int o = 0; o < 24; ++o) {
          acc0[o] = fmaf(tv0, w[o], acc0[o]);
          acc1[o] = fmaf(tv1, w[o], acc1[o]);
        }
      }
    }
  }
  float* ob = h2 + (size_t)b * 48 * HW + (size_t)og * 24 * HW
            + (i0 + ty) * 64 + (j0 + tx);
  #pragma unroll
  for (int o = 0; o < 24; ++o) {
    float bo = bt[og * 24 + o];
    ob[(size_t)o * HW] = acc0[o] + bo;
    ob[(size_t)o * HW + 8 * 64] = acc1[o] + bo;
  }
}

// ---------------------------------------------------------------------------
// K6: 1x1 relu (48->128, W2T rows) -> 1x1 (128->8) -> masked residual.
// P=2: each thread handles pixels pix and pix+256 (same image; 512 px/block).
// Per o-iter: 48 s_load floats feed 96 FMAs.
// ---------------------------------------------------------------------------
__global__ __launch_bounds__(256) void k_head(
    const float* __restrict__ h2, const float* __restrict__ W2T,
    const float* __restrict__ b2, const float* __restrict__ W3,
    const float* __restrict__ b3, const float* __restrict__ x,
    const float* __restrict__ noise, float* __restrict__ x2,
    float* __restrict__ alpha2) {
  int t = threadIdx.x;
  int pix0 = blockIdx.x * 512 + t;
  int pix1 = pix0 + 256;
  int b = pix0 >> 12;                     // 8 blocks per image -> same b
  int hw0 = pix0 & 4095, hw1 = pix1 & 4095;
  float hr0[48], hr1[48];
  const float* hb = h2 + (size_t)b * 48 * HW;
  #pragma unroll
  for (int c = 0; c < 48; ++c) {
    hr0[c] = hb[(size_t)c * HW + hw0];
    hr1[c] = hb[(size_t)c * HW + hw1];
  }
  float dx0[8], dx1[8];
  #pragma unroll
  for (int k = 0; k < 8; ++k) { dx0[k] = b3[k]; dx1[k] = b3[k]; }
  #pragma unroll 2
  for (int o = 0; o < 128; ++o) {
    float v0 = b2[o], v1 = v0;
    const float* w2 = W2T + o * 48;           // contiguous row -> s_load
    #pragma unroll
    for (int c = 0; c < 48; ++c) {
      v0 = fmaf(hr0[c], w2[c], v0);
      v1 = fmaf(hr1[c], w2[c], v1);
    }
    v0 = fmaxf(v0, 0.f);
    v1 = fmaxf(v1, 0.f);
    const float* w3 = W3 + o * 8;
    #pragma unroll
    for (int k = 0; k < 8; ++k) {
      dx0[k] = fmaf(v0, w3[k], dx0[k]);
      dx1[k] = fmaf(v1, w3[k], dx1[k]);
    }
  }
  float m0 = (noise[pix0] <= 0.5f) ? 1.f : 0.f;
  float m1 = (noise[pix1] <= 0.5f) ? 1.f : 0.f;
  const float* xp0 = x + (size_t)pix0 * 8;
  const float* xp1 = x + (size_t)pix1 * 8;
  float* xo0 = x2 + (size_t)pix0 * 8;
  float* xo1 = x2 + (size_t)pix1 * 8;
  float a30 = 0.f, a31 = 0.f;
  #pragma unroll
  for (int k = 0; k < 8; ++k) {
    float v0 = fmaf(dx0[k], m0, xp0[k]);
    float v1 = fmaf(dx1[k], m1, xp1[k]);
    xo0[k] = v0; xo1[k] = v1;
    if (k == 3) { a30 = v0; a31 = v1; }
  }
  alpha2[pix0] = a30;
  alpha2[pix1] = a31;
}

// ---------------------------------------------------------------------------
// K7: post_life maxpool + alive gating -> d_out
// ---------------------------------------------------------------------------
__global__ __launch_bounds__(256) void k_life(
    const float* __restrict__ x2, const float* __restrict__ alpha2,
    const float* __restrict__ prelife, float* __restrict__ out) {
  int pix = blockIdx.x * 256 + threadIdx.x;
  int hw = pix & 4095;
  int h = hw >> 6, w = hw & 63;
  const float* ab = alpha2 + (size_t)(pix - hw);
  float mx = -1e30f;
  #pragma unroll
  for (int di = -1; di <= 1; ++di) {
    if ((unsigned)(h + di) > 63u) continue;
    #pragma unroll
    for (int dj = -1; dj <= 1; ++dj) {
      if ((unsigned)(w + dj) > 63u) continue;
      mx = fmaxf(mx, ab[(h + di) * 64 + (w + dj)]);
    }
  }
  float life = (mx > 0.1f && prelife[pix] > 0.5f) ? 1.f : 0.f;
  const float* xp = x2 + (size_t)pix * 8;
  float* op = out + (size_t)pix * 8;
  #pragma unroll
  for (int k = 0; k < 8; ++k) op[k] = xp[k] * life;
}

// ---------------------------------------------------------------------------
extern "C" void kernel_launch(void* const* d_in, const int* in_sizes, int n_in,
                              void* d_out, int out_size, void* d_ws, size_t ws_size,
                              hipStream_t stream) {
  const float* x     = (const float*)d_in[0];
  const float* noise = (const float*)d_in[1];
  const float* Watt  = (const float*)d_in[2];
  const float* b_att = (const float*)d_in[3];
  const float* W1    = (const float*)d_in[4];
  const float* b1    = (const float*)d_in[5];
  const float* Wt    = (const float*)d_in[6];
  const float* bt    = (const float*)d_in[7];
  const float* W2    = (const float*)d_in[8];
  const float* b2    = (const float*)d_in[9];
  const float* W3    = (const float*)d_in[10];
  const float* b3    = (const float*)d_in[11];
  float* out = (float*)d_out;

  float* ws = (float*)d_ws;
  size_t o_y   = 0;                       // y_chw [6291456]; later x2+alpha2
  size_t o_y2  = o_y + 6291456;           // y2_chw [18874368]; later h2 [12582912]
  size_t o_h1  = o_y2 + 18874368;         // h1_chw [11808768]
  size_t o_y0  = o_h1 + 11808768;         // y0_hwc [98304]
  size_t o_pre = o_y0 + 98304;            // prelife [262144]
  size_t o_att = o_pre + 262144;          // att_acc[648] + ssq[1]
  size_t o_w2t = o_att + 652;             // W2T [6144]
  float* y_chw   = ws + o_y;
  float* y2_chw  = ws + o_y2;
  float* h2_chw  = ws + o_y2;             // alias: y2 dead after k_conv1
  float* h1_chw  = ws + o_h1;
  float* y0_hwc  = ws + o_y0;
  float* prelife = ws + o_pre;
  float* att_acc = ws + o_att;
  float* ssq     = ws + o_att + 648;
  float* W2T     = ws + o_w2t;
  float* x2      = ws + o_y;              // alias: y dead after k_dw2
  float* alpha2  = ws + o_y + 2097152;

  k_prep<<<1, 256, 0, stream>>>(W2, W2T);
  k_perceive<<<1024, 256, 0, stream>>>(x, y_chw, y0_hwc, prelife, att_acc);
  k_att<<<768, 256, 0, stream>>>(y0_hwc, Watt, att_acc);
  k_dw2<<<1024, 256, 0, stream>>>(y_chw, att_acc, b_att, y2_chw, ssq);
  k_conv1<<<1024, 256, 0, stream>>>(y2_chw, W1, b1, ssq, h1_chw);
  k_convT<<<1024, 256, 0, stream>>>(h1_chw, Wt, bt, h2_chw);
  k_head<<<512, 256, 0, stream>>>(h2_chw, W2T, b2, W3, b3, x, noise, x2, alpha2);
  k_life<<<1024, 256, 0, stream>>>(x2, alpha2, prelife, out);
}